// Round 1
// baseline (164.316 us; speedup 1.0000x reference)
//
#include <hip/hip_runtime.h>
#include <math.h>

#define BQ 8
#define MQ 64
#define REGMAX 16
#define KTOP 10
#define EPSQ 1e-7f
#define APB 512   // anchors per decode block (256 threads x 2)
#define MBUF 1024 // >= bpb*KTOP = 670 for N=34000

__device__ __forceinline__ float frcp(float x) { return __builtin_amdgcn_rcpf(x); }

// Scalar DFL side (odd-N tail fallback only).
__device__ __forceinline__ float dfl_side(const float* __restrict__ p, size_t Ns) {
  float x0 = p[0];
  float x1 = p[Ns];
  float x2 = p[2 * Ns];
  float x3 = p[3 * Ns];
  float x4 = p[4 * Ns];
  float x5 = p[5 * Ns];
  float x6 = p[6 * Ns];
  float x7 = p[7 * Ns];
  float x8 = p[8 * Ns];
  float x9 = p[9 * Ns];
  float x10 = p[10 * Ns];
  float x11 = p[11 * Ns];
  float x12 = p[12 * Ns];
  float x13 = p[13 * Ns];
  float x14 = p[14 * Ns];
  float x15 = p[15 * Ns];
  float mx = fmaxf(fmaxf(fmaxf(fmaxf(x0, x1), fmaxf(x2, x3)),
                         fmaxf(fmaxf(x4, x5), fmaxf(x6, x7))),
                   fmaxf(fmaxf(fmaxf(x8, x9), fmaxf(x10, x11)),
                         fmaxf(fmaxf(x12, x13), fmaxf(x14, x15))));
  float s = 0.f, ws = 0.f, e;
  e = __expf(x0 - mx); s += e;
  e = __expf(x1 - mx); s += e; ws += 1.f * e;
  e = __expf(x2 - mx); s += e; ws += 2.f * e;
  e = __expf(x3 - mx); s += e; ws += 3.f * e;
  e = __expf(x4 - mx); s += e; ws += 4.f * e;
  e = __expf(x5 - mx); s += e; ws += 5.f * e;
  e = __expf(x6 - mx); s += e; ws += 6.f * e;
  e = __expf(x7 - mx); s += e; ws += 7.f * e;
  e = __expf(x8 - mx); s += e; ws += 8.f * e;
  e = __expf(x9 - mx); s += e; ws += 9.f * e;
  e = __expf(x10 - mx); s += e; ws += 10.f * e;
  e = __expf(x11 - mx); s += e; ws += 11.f * e;
  e = __expf(x12 - mx); s += e; ws += 12.f * e;
  e = __expf(x13 - mx); s += e; ws += 13.f * e;
  e = __expf(x14 - mx); s += e; ws += 14.f * e;
  e = __expf(x15 - mx); s += e; ws += 15.f * e;
  return ws * frcp(s);
}

// Two-anchor DFL side: 16 float2 loads (8B/lane coalesced burst), two
// interleaved softmax chains (the .x/.y interleave doubles ILP on the
// otherwise-serial sum chains).
__device__ __forceinline__ float2 dfl_side2(const float* __restrict__ p, size_t Ns) {
  float2 x0 = *(const float2*)(p);
  float2 x1 = *(const float2*)(p + Ns);
  float2 x2 = *(const float2*)(p + 2 * Ns);
  float2 x3 = *(const float2*)(p + 3 * Ns);
  float2 x4 = *(const float2*)(p + 4 * Ns);
  float2 x5 = *(const float2*)(p + 5 * Ns);
  float2 x6 = *(const float2*)(p + 6 * Ns);
  float2 x7 = *(const float2*)(p + 7 * Ns);
  float2 x8 = *(const float2*)(p + 8 * Ns);
  float2 x9 = *(const float2*)(p + 9 * Ns);
  float2 x10 = *(const float2*)(p + 10 * Ns);
  float2 x11 = *(const float2*)(p + 11 * Ns);
  float2 x12 = *(const float2*)(p + 12 * Ns);
  float2 x13 = *(const float2*)(p + 13 * Ns);
  float2 x14 = *(const float2*)(p + 14 * Ns);
  float2 x15 = *(const float2*)(p + 15 * Ns);
  float mxa = fmaxf(fmaxf(fmaxf(fmaxf(x0.x, x1.x), fmaxf(x2.x, x3.x)),
                          fmaxf(fmaxf(x4.x, x5.x), fmaxf(x6.x, x7.x))),
                    fmaxf(fmaxf(fmaxf(x8.x, x9.x), fmaxf(x10.x, x11.x)),
                          fmaxf(fmaxf(x12.x, x13.x), fmaxf(x14.x, x15.x))));
  float mxb = fmaxf(fmaxf(fmaxf(fmaxf(x0.y, x1.y), fmaxf(x2.y, x3.y)),
                          fmaxf(fmaxf(x4.y, x5.y), fmaxf(x6.y, x7.y))),
                    fmaxf(fmaxf(fmaxf(x8.y, x9.y), fmaxf(x10.y, x11.y)),
                          fmaxf(fmaxf(x12.y, x13.y), fmaxf(x14.y, x15.y))));
  float sa = 0.f, wa = 0.f, sb = 0.f, wb = 0.f, e;
  e = __expf(x0.x - mxa); sa += e;
  e = __expf(x0.y - mxb); sb += e;
  e = __expf(x1.x - mxa); sa += e; wa += 1.f * e;
  e = __expf(x1.y - mxb); sb += e; wb += 1.f * e;
  e = __expf(x2.x - mxa); sa += e; wa += 2.f * e;
  e = __expf(x2.y - mxb); sb += e; wb += 2.f * e;
  e = __expf(x3.x - mxa); sa += e; wa += 3.f * e;
  e = __expf(x3.y - mxb); sb += e; wb += 3.f * e;
  e = __expf(x4.x - mxa); sa += e; wa += 4.f * e;
  e = __expf(x4.y - mxb); sb += e; wb += 4.f * e;
  e = __expf(x5.x - mxa); sa += e; wa += 5.f * e;
  e = __expf(x5.y - mxb); sb += e; wb += 5.f * e;
  e = __expf(x6.x - mxa); sa += e; wa += 6.f * e;
  e = __expf(x6.y - mxb); sb += e; wb += 6.f * e;
  e = __expf(x7.x - mxa); sa += e; wa += 7.f * e;
  e = __expf(x7.y - mxb); sb += e; wb += 7.f * e;
  e = __expf(x8.x - mxa); sa += e; wa += 8.f * e;
  e = __expf(x8.y - mxb); sb += e; wb += 8.f * e;
  e = __expf(x9.x - mxa); sa += e; wa += 9.f * e;
  e = __expf(x9.y - mxb); sb += e; wb += 9.f * e;
  e = __expf(x10.x - mxa); sa += e; wa += 10.f * e;
  e = __expf(x10.y - mxb); sb += e; wb += 10.f * e;
  e = __expf(x11.x - mxa); sa += e; wa += 11.f * e;
  e = __expf(x11.y - mxb); sb += e; wb += 11.f * e;
  e = __expf(x12.x - mxa); sa += e; wa += 12.f * e;
  e = __expf(x12.y - mxb); sb += e; wb += 12.f * e;
  e = __expf(x13.x - mxa); sa += e; wa += 13.f * e;
  e = __expf(x13.y - mxb); sb += e; wb += 13.f * e;
  e = __expf(x14.x - mxa); sa += e; wa += 14.f * e;
  e = __expf(x14.y - mxb); sb += e; wb += 14.f * e;
  e = __expf(x15.x - mxa); sa += e; wa += 15.f * e;
  e = __expf(x15.y - mxb); sb += e; wb += 15.f * e;
  return make_float2(wa * frcp(sa), wb * frcp(sb));
}

// ---------------- kernel 1: decode (float2, 2 anchors/thread) + screen + per-block top-10 ----------------
__global__ __launch_bounds__(256) void decode_topk_kernel(
    const float* __restrict__ boxes, const float* __restrict__ scores,
    const float* __restrict__ targets, unsigned int* __restrict__ iou_bits,
    uint2* __restrict__ cand, float* __restrict__ bcePartial,
    unsigned int* __restrict__ ctr, int N, int bpb) {
  const int tid = threadIdx.x;
  const int b = blockIdx.x / bpb;
  const int blk = blockIdx.x - b * bpb;
  const int a0 = blk * APB;
  const int w = tid >> 6;
  const int l = tid & 63;

  __shared__ float4 s_sv[APB];
  __shared__ float s_at[APB];
  __shared__ int s_ix[APB];
  __shared__ float s_hv[4 * MQ * KTOP];
  __shared__ int s_hi[4 * MQ * KTOP];
  __shared__ uint2 s_mg[MQ * KTOP];
  __shared__ int s_cnt;
  __shared__ float s_bce;
  if (tid == 0) { s_cnt = 0; s_bce = 0.f; }
  // zero the merge-done counter; all decode blocks complete before merge
  // launches (stream order), so any decode block may do this.
  if (blockIdx.x == 0 && tid == 0) *ctr = 0u;
  __syncthreads();

  // ---- phase 1: decode 2 anchors/thread, 4 sides each, float2 bursts ----
  const int n0 = a0 + 2 * tid;
  float bce0 = 0.f;
  if (n0 < N) {
    const size_t i = (size_t)b * N + n0;
    const size_t Ns = (size_t)N;
    const float* base = boxes + (size_t)(b * 64) * Ns + n0;
    if (n0 + 1 < N) {
      iou_bits[i] = 0u;
      iou_bits[i + 1] = 0u;
      float2 sc = *(const float2*)(scores + i);
      bce0 = fmaxf(sc.x, 0.f) + log1pf(__expf(-fabsf(sc.x))) +
             fmaxf(sc.y, 0.f) + log1pf(__expf(-fabsf(sc.y)));
      float2 ev0 = dfl_side2(base, Ns);
      float2 ev1 = dfl_side2(base + 16 * Ns, Ns);
      float2 ev2 = dfl_side2(base + 32 * Ns, Ns);
      float2 ev3 = dfl_side2(base + 48 * Ns, Ns);
      float w1 = ev2.x - ev0.x, h1 = ev3.x - ev1.x;
      if (w1 > 0.f && h1 > 0.f) {
        int slot = atomicAdd(&s_cnt, 1);
        s_sv[slot] = make_float4(ev0.x, ev1.x, ev2.x, ev3.x);
        s_at[slot] = atanf(w1 * frcp(h1 + EPSQ));
        s_ix[slot] = n0;
      }
      float w1b = ev2.y - ev0.y, h1b = ev3.y - ev1.y;
      if (w1b > 0.f && h1b > 0.f) {
        int slot = atomicAdd(&s_cnt, 1);
        s_sv[slot] = make_float4(ev0.y, ev1.y, ev2.y, ev3.y);
        s_at[slot] = atanf(w1b * frcp(h1b + EPSQ));
        s_ix[slot] = n0 + 1;
      }
    } else {  // odd-N tail: single anchor, scalar loads (no OOB float2)
      iou_bits[i] = 0u;
      float sc = scores[i];
      bce0 = fmaxf(sc, 0.f) + log1pf(__expf(-fabsf(sc)));
      float ev0 = dfl_side(base, Ns);
      float ev1 = dfl_side(base + 16 * Ns, Ns);
      float ev2 = dfl_side(base + 32 * Ns, Ns);
      float ev3 = dfl_side(base + 48 * Ns, Ns);
      float w1 = ev2 - ev0, h1 = ev3 - ev1;
      if (w1 > 0.f && h1 > 0.f) {
        int slot = atomicAdd(&s_cnt, 1);
        s_sv[slot] = make_float4(ev0, ev1, ev2, ev3);
        s_at[slot] = atanf(w1 * frcp(h1 + EPSQ));
        s_ix[slot] = n0;
      }
    }
  }
#pragma unroll
  for (int d = 1; d < 64; d <<= 1) bce0 += __shfl_xor(bce0, d, 64);
  if (l == 0) atomicAdd(&s_bce, bce0);
  __syncthreads();
  const int nsurv = s_cnt;
  if (tid == 0) bcePartial[blockIdx.x] = s_bce;  // always written: no memset needed

  // ---- phase 2: lane = target; wave w scans its survivor quarter (LDS broadcast) ----
  const float4 t = ((const float4*)targets)[b * MQ + l];
  const float x21 = t.x, y21 = t.y, x22 = t.z, y22 = t.w;
  const float w2 = x22 - x21, h2 = y22 - y21;
  const float atan_t = atanf(w2 * frcp(h2 + EPSQ));
  const float area2 = w2 * h2, sumx2 = x21 + x22, sumy2 = y21 + y22;
  const float CPI = 4.0f / (float)(M_PI * M_PI);

  float hv0 = 0.f, hv1 = 0.f, hv2 = 0.f, hv3 = 0.f, hv4 = 0.f;
  float hv5 = 0.f, hv6 = 0.f, hv7 = 0.f, hv8 = 0.f, hv9 = 0.f;
  int hi0 = 0, hi1 = 0, hi2 = 0, hi3 = 0, hi4 = 0;
  int hi5 = 0, hi6 = 0, hi7 = 0, hi8 = 0, hi9 = 0;

  const int qlen = (nsurv + 3) >> 2;
  const int j0 = w * qlen;
  const int j1 = min(nsurv, j0 + qlen);
  for (int j = j0; j < j1; ++j) {
    float4 p = s_sv[j];  // same addr across lanes -> LDS broadcast
    float pa = s_at[j];
    int ixj = s_ix[j];
    float x11 = p.x, y11 = p.y, x12 = p.z, y12 = p.w;
    float w1 = x12 - x11, h1 = y12 - y11;
    float iw = fmaxf(fminf(x12, x22) - fmaxf(x11, x21), 0.f);
    float ih = fmaxf(fminf(y12, y22) - fmaxf(y11, y21), 0.f);
    float inter = iw * ih;
    float uni = w1 * h1 + area2 - inter + EPSQ;
    float iou = inter * frcp(uni);
    float cw = fmaxf(x12, x22) - fminf(x11, x21);
    float ch = fmaxf(y12, y22) - fminf(y11, y21);
    float c2 = cw * cw + ch * ch + EPSQ;
    float dx = sumx2 - x11 - x12;
    float dy = sumy2 - y11 - y12;
    float rho2 = (dx * dx + dy * dy) * 0.25f;
    float da = atan_t - pa;
    float v = CPI * da * da;
    float alpha = v * frcp(v - iou + 1.f + EPSQ);
    float ciou = iou - rho2 * frcp(c2) - alpha * v;
    if (ciou > hv9) {
      float cv = ciou;
      int ci = ixj;
#define INS(vk, ik)                         \
  {                                         \
    bool gt = cv > vk;                      \
    float tv_ = vk; int ti_ = ik;           \
    vk = gt ? cv : vk; ik = gt ? ci : ik;   \
    cv = gt ? tv_ : cv; ci = gt ? ti_ : ci; \
  }
      INS(hv0, hi0) INS(hv1, hi1) INS(hv2, hi2) INS(hv3, hi3) INS(hv4, hi4)
      INS(hv5, hi5) INS(hv6, hi6) INS(hv7, hi7) INS(hv8, hi8) INS(hv9, hi9)
#undef INS
    }
  }
  const int hb = (w * MQ + l) * KTOP;
  s_hv[hb + 0] = hv0; s_hi[hb + 0] = hi0;
  s_hv[hb + 1] = hv1; s_hi[hb + 1] = hi1;
  s_hv[hb + 2] = hv2; s_hi[hb + 2] = hi2;
  s_hv[hb + 3] = hv3; s_hi[hb + 3] = hi3;
  s_hv[hb + 4] = hv4; s_hi[hb + 4] = hi4;
  s_hv[hb + 5] = hv5; s_hi[hb + 5] = hi5;
  s_hv[hb + 6] = hv6; s_hi[hb + 6] = hi6;
  s_hv[hb + 7] = hv7; s_hi[hb + 7] = hi7;
  s_hv[hb + 8] = hv8; s_hi[hb + 8] = hi8;
  s_hv[hb + 9] = hv9; s_hi[hb + 9] = hi9;
  __syncthreads();

  // ---- phase 3: wave 0, lane m: 4-way merge -> s_mg ----
  if (w == 0) {
    const int m = l;
    int p0 = 0, p1 = 0, p2 = 0, p3 = 0;
    for (int r = 0; r < KTOP; ++r) {
      float c0 = s_hv[(0 * MQ + m) * KTOP + p0];
      float c1 = s_hv[(1 * MQ + m) * KTOP + p1];
      float c2m = s_hv[(2 * MQ + m) * KTOP + p2];
      float c3 = s_hv[(3 * MQ + m) * KTOP + p3];
      float best = c0; int bw = 0;
      if (c1 > best) { best = c1; bw = 1; }
      if (c2m > best) { best = c2m; bw = 2; }
      if (c3 > best) { best = c3; bw = 3; }
      int psel = (bw == 0) ? p0 : (bw == 1) ? p1 : (bw == 2) ? p2 : p3;
      int bidx = s_hi[(bw * MQ + m) * KTOP + psel];
      s_mg[m * KTOP + r] = make_uint2(__float_as_uint(best), (unsigned)bidx);
      if (bw == 0) p0 = min(p0 + 1, KTOP - 1);
      else if (bw == 1) p1 = min(p1 + 1, KTOP - 1);
      else if (bw == 2) p2 = min(p2 + 1, KTOP - 1);
      else p3 = min(p3 + 1, KTOP - 1);
    }
  }
  __syncthreads();
  // copy-out, TRANSPOSED layout [b][m][blk][r] so merge reads contiguously
  for (int sl = tid; sl < MQ * KTOP; sl += 256) {
    int m = sl / KTOP;
    int r = sl - m * KTOP;
    cand[((size_t)(b * MQ + m) * bpb + blk) * KTOP + r] = s_mg[sl];
  }
}

// ---------------- exact top-10 of LDS buffer (wave 0 only) ----------------
__device__ __forceinline__ void select_top10(
    float* s_bv, int* s_bi, float* s_winv, int* s_wini,
    int* s_cnt, int c, int tid) {
  if (tid < 64) {
    for (int r = 0; r < KTOP; ++r) {
      float bv = 0.f;
      int bs = 0xffff;
      for (int sl = tid; sl < c; sl += 64) {
        float v = s_bv[sl];
        if (v > bv) { bv = v; bs = sl; }
      }
      unsigned long long key =
          ((unsigned long long)__float_as_uint(bv) << 32) | (unsigned int)bs;
#pragma unroll
      for (int d = 1; d < 64; d <<= 1) {
        unsigned long long o = __shfl_xor(key, d, 64);
        if (o > key) key = o;
      }
      if (tid == 0) {
        float wv = __uint_as_float((unsigned int)(key >> 32));
        int ws = (int)(key & 0xffffu);
        s_winv[r] = wv;
        if (wv > 0.f && ws != 0xffff) {
          s_wini[r] = s_bi[ws];
          s_bv[ws] = 0.f;
        } else {
          s_wini[r] = 0;
        }
      }
    }
    if (tid < KTOP) { s_bv[tid] = s_winv[tid]; s_bi[tid] = s_wini[tid]; }
    if (tid == 0) *s_cnt = KTOP;
  }
}

// ---------------- kernel 2: merge 67x10 per (b,m) -> top-10; scatter + exact delta;
// last block finalizes (no separate finalize dispatch, no memset dispatch) ----------------
__global__ __launch_bounds__(256) void merge_kernel(
    const uint2* __restrict__ cand, const float* __restrict__ scores,
    unsigned int* __restrict__ iou_bits, const float* __restrict__ bcePartial,
    float* __restrict__ mergePartial, unsigned int* __restrict__ ctr,
    float* __restrict__ out, int N, int bpb) {
  const int bm = blockIdx.x;
  const int b = bm >> 6;
  const int tid = threadIdx.x;
  const int NC = bpb * KTOP;  // 670 for N=34000

  __shared__ float s_bv[MBUF];
  __shared__ int s_bi[MBUF];
  __shared__ float s_winv[KTOP];
  __shared__ int s_wini[KTOP];
  __shared__ int s_cnt;
  __shared__ float s_d[3];
  __shared__ int s_last;
  __shared__ float s_box[BQ], s_obj[BQ];
  if (tid == 0) s_cnt = 0;
  if (tid < 3) s_d[tid] = 0.f;
  __syncthreads();

  const uint2* cbase = cand + (size_t)bm * NC;  // contiguous per (b,m)
  for (int k2 = tid; k2 < NC; k2 += 256) {
    uint2 e = cbase[k2];
    float v = __uint_as_float(e.x);
    if (v > 0.f) {
      int slot = atomicAdd(&s_cnt, 1);  // slot < NC <= MBUF
      s_bv[slot] = v;
      s_bi[slot] = (int)e.y;
    }
  }
  __syncthreads();
  int c = s_cnt;
  __syncthreads();
  if (c > KTOP) {
    select_top10(s_bv, s_bi, s_winv, s_wini, &s_cnt, c, tid);
    __syncthreads();
    c = KTOP;
  }
  if (tid < KTOP && tid < c) {
    float v = s_bv[tid];
    if (v > 0.f) {
      int ix = s_bi[tid];
      unsigned int vb = __float_as_uint(v);
      unsigned int old = atomicMax(&iou_bits[(size_t)b * N + ix], vb);
      if (old < vb) {  // raised this anchor's max: exact delta (telescopes)
        float vold = __uint_as_float(old);  // 0.f when old==0
        bool was = (old != 0u);
        atomicAdd(&s_d[0], was ? (vold - v) : (1.f - v));
        if (!was) atomicAdd(&s_d[1], 1.f);
        atomicAdd(&s_d[2], -scores[(size_t)b * N + ix] * (v - vold));
      }
    }
  }
  __syncthreads();
  if (tid == 0) {
    float4* mp = (float4*)(mergePartial + (size_t)bm * 4);
    *mp = make_float4(s_d[0], s_d[1], s_d[2], 0.f);  // always written
    __threadfence();                                  // release partials
    unsigned int done = atomicAdd(ctr, 1u);           // device-scope
    s_last = (done == (unsigned)(gridDim.x - 1)) ? 1 : 0;
  }
  __syncthreads();
  if (s_last) {
    __threadfence();  // acquire: all other blocks' partials now visible
    if (tid < BQ) {
      const int bb = tid;
      volatile const float* mp = mergePartial;
      float sbox = 0.f, snp = 0.f, sbce = 0.f;
      for (int mm = 0; mm < MQ; ++mm) {
        int idx = (bb * MQ + mm) * 4;
        sbox += mp[idx];
        snp += mp[idx + 1];
        sbce += mp[idx + 2];
      }
      volatile const float* bp = bcePartial;
      for (int k2 = 0; k2 < bpb; ++k2) sbce += bp[bb * bpb + k2];
      s_box[bb] = (snp > 0.f) ? sbox / fmaxf(snp, 1.f) : 0.f;
      s_obj[bb] = sbce / (float)N;
    }
    __syncthreads();
    if (tid == 0) {
      float box = 0.f, obj = 0.f;
      for (int bb = 0; bb < BQ; ++bb) { box += s_box[bb]; obj += s_obj[bb]; }
      out[0] = (7.5f * box + obj) / (float)BQ;
      out[1] = box;
      out[2] = obj;
    }
  }
}

extern "C" void kernel_launch(void* const* d_in, const int* in_sizes, int n_in,
                              void* d_out, int out_size, void* d_ws, size_t ws_size,
                              hipStream_t stream) {
  const float* boxes = (const float*)d_in[0];
  const float* scores = (const float*)d_in[1];
  const float* targets = (const float*)d_in[2];
  float* out = (float*)d_out;
  const int N = in_sizes[1] / BQ;  // scores is [B, N]

  const int bpb = (N + APB - 1) / APB;  // 67 for N=34000
  const int nblk = BQ * bpb;            // 536 decode blocks

  char* ws = (char*)d_ws;
  size_t cand_bytes = (size_t)BQ * MQ * bpb * KTOP * sizeof(uint2);
  size_t iou_bytes = (size_t)BQ * N * sizeof(unsigned int);
  size_t bce_bytes = (((size_t)nblk * sizeof(float)) + 255) & ~(size_t)255;
  size_t mp_bytes = (size_t)BQ * MQ * 4 * sizeof(float);

  uint2* cand = (uint2*)ws;                    ws += cand_bytes;
  unsigned int* iou_bits = (unsigned int*)ws;  ws += iou_bytes;
  float* bcePartial = (float*)ws;              ws += bce_bytes;
  float* mergePartial = (float*)ws;            ws += mp_bytes;
  unsigned int* ctr = (unsigned int*)ws;

  // 2 dispatches total: no memset (all accumulators are always-written
  // per-block partials; ctr is zeroed by decode, which fully precedes merge
  // by stream order), no finalize (folded into merge's last block).
  decode_topk_kernel<<<nblk, 256, 0, stream>>>(boxes, scores, targets,
                                               iou_bits, cand, bcePartial, ctr, N, bpb);
  merge_kernel<<<BQ * MQ, 256, 0, stream>>>(cand, scores, iou_bits, bcePartial,
                                            mergePartial, ctr, out, N, bpb);
}

// Round 2
// 159.276 us; speedup vs baseline: 1.0316x; 1.0316x over previous
//
#include <hip/hip_runtime.h>
#include <math.h>

#define BQ 8
#define MQ 64
#define REGMAX 16
#define KTOP 10
#define EPSQ 1e-7f
#define APB 1024  // anchors per decode block (256 threads x 4)
#define MBUF 1024 // >= bpb*KTOP = 340 for N=34000

__device__ __forceinline__ float frcp(float x) { return __builtin_amdgcn_rcpf(x); }

// Scalar DFL side (tail / unaligned-N fallback only).
__device__ __forceinline__ float dfl_side(const float* __restrict__ p, size_t Ns) {
  float x0 = p[0];
  float x1 = p[Ns];
  float x2 = p[2 * Ns];
  float x3 = p[3 * Ns];
  float x4 = p[4 * Ns];
  float x5 = p[5 * Ns];
  float x6 = p[6 * Ns];
  float x7 = p[7 * Ns];
  float x8 = p[8 * Ns];
  float x9 = p[9 * Ns];
  float x10 = p[10 * Ns];
  float x11 = p[11 * Ns];
  float x12 = p[12 * Ns];
  float x13 = p[13 * Ns];
  float x14 = p[14 * Ns];
  float x15 = p[15 * Ns];
  float mx = fmaxf(fmaxf(fmaxf(fmaxf(x0, x1), fmaxf(x2, x3)),
                         fmaxf(fmaxf(x4, x5), fmaxf(x6, x7))),
                   fmaxf(fmaxf(fmaxf(x8, x9), fmaxf(x10, x11)),
                         fmaxf(fmaxf(x12, x13), fmaxf(x14, x15))));
  float s = 0.f, ws = 0.f, e;
  e = __expf(x0 - mx); s += e;
  e = __expf(x1 - mx); s += e; ws += 1.f * e;
  e = __expf(x2 - mx); s += e; ws += 2.f * e;
  e = __expf(x3 - mx); s += e; ws += 3.f * e;
  e = __expf(x4 - mx); s += e; ws += 4.f * e;
  e = __expf(x5 - mx); s += e; ws += 5.f * e;
  e = __expf(x6 - mx); s += e; ws += 6.f * e;
  e = __expf(x7 - mx); s += e; ws += 7.f * e;
  e = __expf(x8 - mx); s += e; ws += 8.f * e;
  e = __expf(x9 - mx); s += e; ws += 9.f * e;
  e = __expf(x10 - mx); s += e; ws += 10.f * e;
  e = __expf(x11 - mx); s += e; ws += 11.f * e;
  e = __expf(x12 - mx); s += e; ws += 12.f * e;
  e = __expf(x13 - mx); s += e; ws += 13.f * e;
  e = __expf(x14 - mx); s += e; ws += 14.f * e;
  e = __expf(x15 - mx); s += e; ws += 15.f * e;
  return ws * frcp(s);
}

// Four-anchor DFL side: 16 float4 loads (16B/lane -> 1KB/wave segments),
// four interleaved softmax chains for ILP on the serial sum chains.
__device__ __forceinline__ float4 dfl_side4(const float* __restrict__ p, size_t Ns) {
  float4 x0 = *(const float4*)(p);
  float4 x1 = *(const float4*)(p + Ns);
  float4 x2 = *(const float4*)(p + 2 * Ns);
  float4 x3 = *(const float4*)(p + 3 * Ns);
  float4 x4 = *(const float4*)(p + 4 * Ns);
  float4 x5 = *(const float4*)(p + 5 * Ns);
  float4 x6 = *(const float4*)(p + 6 * Ns);
  float4 x7 = *(const float4*)(p + 7 * Ns);
  float4 x8 = *(const float4*)(p + 8 * Ns);
  float4 x9 = *(const float4*)(p + 9 * Ns);
  float4 x10 = *(const float4*)(p + 10 * Ns);
  float4 x11 = *(const float4*)(p + 11 * Ns);
  float4 x12 = *(const float4*)(p + 12 * Ns);
  float4 x13 = *(const float4*)(p + 13 * Ns);
  float4 x14 = *(const float4*)(p + 14 * Ns);
  float4 x15 = *(const float4*)(p + 15 * Ns);
#define MAX16(c)                                                        \
  fmaxf(fmaxf(fmaxf(fmaxf(x0.c, x1.c), fmaxf(x2.c, x3.c)),              \
              fmaxf(fmaxf(x4.c, x5.c), fmaxf(x6.c, x7.c))),             \
        fmaxf(fmaxf(fmaxf(x8.c, x9.c), fmaxf(x10.c, x11.c)),            \
              fmaxf(fmaxf(x12.c, x13.c), fmaxf(x14.c, x15.c))))
  float mxa = MAX16(x);
  float mxb = MAX16(y);
  float mxc = MAX16(z);
  float mxd = MAX16(w);
#undef MAX16
  float sa = 0.f, wa = 0.f, sb = 0.f, wb = 0.f;
  float sc = 0.f, wc = 0.f, sd = 0.f, wd = 0.f;
  float e;
#define STEP(K, XK)                                      \
  e = __expf(XK.x - mxa); sa += e; wa += (float)K * e;   \
  e = __expf(XK.y - mxb); sb += e; wb += (float)K * e;   \
  e = __expf(XK.z - mxc); sc += e; wc += (float)K * e;   \
  e = __expf(XK.w - mxd); sd += e; wd += (float)K * e;
  STEP(0, x0) STEP(1, x1) STEP(2, x2) STEP(3, x3)
  STEP(4, x4) STEP(5, x5) STEP(6, x6) STEP(7, x7)
  STEP(8, x8) STEP(9, x9) STEP(10, x10) STEP(11, x11)
  STEP(12, x12) STEP(13, x13) STEP(14, x14) STEP(15, x15)
#undef STEP
  return make_float4(wa * frcp(sa), wb * frcp(sb), wc * frcp(sc), wd * frcp(sd));
}

// ---------------- kernel 1: decode (float4, 4 anchors/thread) + screen + per-block top-10 ----------------
__global__ __launch_bounds__(256) void decode_topk_kernel(
    const float* __restrict__ boxes, const float* __restrict__ scores,
    const float* __restrict__ targets, unsigned int* __restrict__ iou_bits,
    uint2* __restrict__ cand, float* __restrict__ bcePartial,
    unsigned int* __restrict__ ctr, int N, int bpb) {
  const int tid = threadIdx.x;
  const int b = blockIdx.x / bpb;
  const int blk = blockIdx.x - b * bpb;
  const int a0 = blk * APB;
  const int w = tid >> 6;
  const int l = tid & 63;

  __shared__ float4 s_sv[APB];
  __shared__ float s_at[APB];
  __shared__ int s_ix[APB];
  __shared__ float s_hv[4 * MQ * KTOP];
  __shared__ int s_hi[4 * MQ * KTOP];
  __shared__ uint2 s_mg[MQ * KTOP];
  __shared__ int s_cnt;
  __shared__ float s_bce;
  if (tid == 0) { s_cnt = 0; s_bce = 0.f; }
  // zero the merge-done counter; decode fully precedes merge (stream order).
  if (blockIdx.x == 0 && tid == 0) *ctr = 0u;
  __syncthreads();

  auto emit = [&](float e0, float e1, float e2, float e3, int n) {
    float w1 = e2 - e0, h1 = e3 - e1;
    if (w1 > 0.f && h1 > 0.f) {  // else ciou<=0 vs every target (ref masks topv>0)
      int slot = atomicAdd(&s_cnt, 1);
      s_sv[slot] = make_float4(e0, e1, e2, e3);
      s_at[slot] = atanf(w1 * frcp(h1 + EPSQ));
      s_ix[slot] = n;
    }
  };

  // ---- phase 1: decode 4 anchors/thread, 4 sides each, float4 bursts ----
  const int n0 = a0 + 4 * tid;
  float bce0 = 0.f;
  if (n0 < N) {
    const size_t i = (size_t)b * N + n0;
    const size_t Ns = (size_t)N;
    const float* base = boxes + (size_t)(b * 64) * Ns + n0;
    if ((N & 3) == 0 && n0 + 3 < N) {
      *(uint4*)(iou_bits + i) = make_uint4(0u, 0u, 0u, 0u);
      float4 sc4 = *(const float4*)(scores + i);
      bce0 = fmaxf(sc4.x, 0.f) + log1pf(__expf(-fabsf(sc4.x))) +
             fmaxf(sc4.y, 0.f) + log1pf(__expf(-fabsf(sc4.y))) +
             fmaxf(sc4.z, 0.f) + log1pf(__expf(-fabsf(sc4.z))) +
             fmaxf(sc4.w, 0.f) + log1pf(__expf(-fabsf(sc4.w)));
      float4 ev0 = dfl_side4(base, Ns);
      float4 ev1 = dfl_side4(base + 16 * Ns, Ns);
      float4 ev2 = dfl_side4(base + 32 * Ns, Ns);
      float4 ev3 = dfl_side4(base + 48 * Ns, Ns);
      emit(ev0.x, ev1.x, ev2.x, ev3.x, n0 + 0);
      emit(ev0.y, ev1.y, ev2.y, ev3.y, n0 + 1);
      emit(ev0.z, ev1.z, ev2.z, ev3.z, n0 + 2);
      emit(ev0.w, ev1.w, ev2.w, ev3.w, n0 + 3);
    } else {  // tail / unaligned N: per-anchor scalar path
      for (int k = 0; k < 4; ++k) {
        int n = n0 + k;
        if (n >= N) break;
        iou_bits[i + k] = 0u;
        float sc = scores[i + k];
        bce0 += fmaxf(sc, 0.f) + log1pf(__expf(-fabsf(sc)));
        const float* bp = base + k;
        float ev0 = dfl_side(bp, Ns);
        float ev1 = dfl_side(bp + 16 * Ns, Ns);
        float ev2 = dfl_side(bp + 32 * Ns, Ns);
        float ev3 = dfl_side(bp + 48 * Ns, Ns);
        emit(ev0, ev1, ev2, ev3, n);
      }
    }
  }
#pragma unroll
  for (int d = 1; d < 64; d <<= 1) bce0 += __shfl_xor(bce0, d, 64);
  if (l == 0) atomicAdd(&s_bce, bce0);
  __syncthreads();
  const int nsurv = s_cnt;
  if (tid == 0) bcePartial[blockIdx.x] = s_bce;  // always written: no memset needed

  // ---- phase 2: lane = target; wave w scans its survivor quarter (LDS broadcast) ----
  const float4 t = ((const float4*)targets)[b * MQ + l];
  const float x21 = t.x, y21 = t.y, x22 = t.z, y22 = t.w;
  const float w2 = x22 - x21, h2 = y22 - y21;
  const float atan_t = atanf(w2 * frcp(h2 + EPSQ));
  const float area2 = w2 * h2, sumx2 = x21 + x22, sumy2 = y21 + y22;
  const float CPI = 4.0f / (float)(M_PI * M_PI);

  float hv0 = 0.f, hv1 = 0.f, hv2 = 0.f, hv3 = 0.f, hv4 = 0.f;
  float hv5 = 0.f, hv6 = 0.f, hv7 = 0.f, hv8 = 0.f, hv9 = 0.f;
  int hi0 = 0, hi1 = 0, hi2 = 0, hi3 = 0, hi4 = 0;
  int hi5 = 0, hi6 = 0, hi7 = 0, hi8 = 0, hi9 = 0;

  const int qlen = (nsurv + 3) >> 2;
  const int j0 = w * qlen;
  const int j1 = min(nsurv, j0 + qlen);
  for (int j = j0; j < j1; ++j) {
    float4 p = s_sv[j];  // same addr across lanes -> LDS broadcast
    float pa = s_at[j];
    int ixj = s_ix[j];
    float x11 = p.x, y11 = p.y, x12 = p.z, y12 = p.w;
    float w1 = x12 - x11, h1 = y12 - y11;
    float iw = fmaxf(fminf(x12, x22) - fmaxf(x11, x21), 0.f);
    float ih = fmaxf(fminf(y12, y22) - fmaxf(y11, y21), 0.f);
    float inter = iw * ih;
    float uni = w1 * h1 + area2 - inter + EPSQ;
    float iou = inter * frcp(uni);
    float cw = fmaxf(x12, x22) - fminf(x11, x21);
    float ch = fmaxf(y12, y22) - fminf(y11, y21);
    float c2 = cw * cw + ch * ch + EPSQ;
    float dx = sumx2 - x11 - x12;
    float dy = sumy2 - y11 - y12;
    float rho2 = (dx * dx + dy * dy) * 0.25f;
    float da = atan_t - pa;
    float v = CPI * da * da;
    float alpha = v * frcp(v - iou + 1.f + EPSQ);
    float ciou = iou - rho2 * frcp(c2) - alpha * v;
    if (ciou > hv9) {
      float cv = ciou;
      int ci = ixj;
#define INS(vk, ik)                         \
  {                                         \
    bool gt = cv > vk;                      \
    float tv_ = vk; int ti_ = ik;           \
    vk = gt ? cv : vk; ik = gt ? ci : ik;   \
    cv = gt ? tv_ : cv; ci = gt ? ti_ : ci; \
  }
      INS(hv0, hi0) INS(hv1, hi1) INS(hv2, hi2) INS(hv3, hi3) INS(hv4, hi4)
      INS(hv5, hi5) INS(hv6, hi6) INS(hv7, hi7) INS(hv8, hi8) INS(hv9, hi9)
#undef INS
    }
  }
  const int hb = (w * MQ + l) * KTOP;
  s_hv[hb + 0] = hv0; s_hi[hb + 0] = hi0;
  s_hv[hb + 1] = hv1; s_hi[hb + 1] = hi1;
  s_hv[hb + 2] = hv2; s_hi[hb + 2] = hi2;
  s_hv[hb + 3] = hv3; s_hi[hb + 3] = hi3;
  s_hv[hb + 4] = hv4; s_hi[hb + 4] = hi4;
  s_hv[hb + 5] = hv5; s_hi[hb + 5] = hi5;
  s_hv[hb + 6] = hv6; s_hi[hb + 6] = hi6;
  s_hv[hb + 7] = hv7; s_hi[hb + 7] = hi7;
  s_hv[hb + 8] = hv8; s_hi[hb + 8] = hi8;
  s_hv[hb + 9] = hv9; s_hi[hb + 9] = hi9;
  __syncthreads();

  // ---- phase 3: wave 0, lane m: 4-way merge -> s_mg ----
  if (w == 0) {
    const int m = l;
    int p0 = 0, p1 = 0, p2 = 0, p3 = 0;
    for (int r = 0; r < KTOP; ++r) {
      float c0 = s_hv[(0 * MQ + m) * KTOP + p0];
      float c1 = s_hv[(1 * MQ + m) * KTOP + p1];
      float c2m = s_hv[(2 * MQ + m) * KTOP + p2];
      float c3 = s_hv[(3 * MQ + m) * KTOP + p3];
      float best = c0; int bw = 0;
      if (c1 > best) { best = c1; bw = 1; }
      if (c2m > best) { best = c2m; bw = 2; }
      if (c3 > best) { best = c3; bw = 3; }
      int psel = (bw == 0) ? p0 : (bw == 1) ? p1 : (bw == 2) ? p2 : p3;
      int bidx = s_hi[(bw * MQ + m) * KTOP + psel];
      s_mg[m * KTOP + r] = make_uint2(__float_as_uint(best), (unsigned)bidx);
      if (bw == 0) p0 = min(p0 + 1, KTOP - 1);
      else if (bw == 1) p1 = min(p1 + 1, KTOP - 1);
      else if (bw == 2) p2 = min(p2 + 1, KTOP - 1);
      else p3 = min(p3 + 1, KTOP - 1);
    }
  }
  __syncthreads();
  // copy-out, TRANSPOSED layout [b][m][blk][r] so merge reads contiguously
  for (int sl = tid; sl < MQ * KTOP; sl += 256) {
    int m = sl / KTOP;
    int r = sl - m * KTOP;
    cand[((size_t)(b * MQ + m) * bpb + blk) * KTOP + r] = s_mg[sl];
  }
}

// ---------------- exact top-10 of LDS buffer (wave 0 only) ----------------
__device__ __forceinline__ void select_top10(
    float* s_bv, int* s_bi, float* s_winv, int* s_wini,
    int* s_cnt, int c, int tid) {
  if (tid < 64) {
    for (int r = 0; r < KTOP; ++r) {
      float bv = 0.f;
      int bs = 0xffff;
      for (int sl = tid; sl < c; sl += 64) {
        float v = s_bv[sl];
        if (v > bv) { bv = v; bs = sl; }
      }
      unsigned long long key =
          ((unsigned long long)__float_as_uint(bv) << 32) | (unsigned int)bs;
#pragma unroll
      for (int d = 1; d < 64; d <<= 1) {
        unsigned long long o = __shfl_xor(key, d, 64);
        if (o > key) key = o;
      }
      if (tid == 0) {
        float wv = __uint_as_float((unsigned int)(key >> 32));
        int ws = (int)(key & 0xffffu);
        s_winv[r] = wv;
        if (wv > 0.f && ws != 0xffff) {
          s_wini[r] = s_bi[ws];
          s_bv[ws] = 0.f;
        } else {
          s_wini[r] = 0;
        }
      }
    }
    if (tid < KTOP) { s_bv[tid] = s_winv[tid]; s_bi[tid] = s_wini[tid]; }
    if (tid == 0) *s_cnt = KTOP;
  }
}

// ---------------- kernel 2: merge 34x10 per (b,m) -> top-10; scatter + exact delta;
// last block finalizes with a PARALLEL reduction (the round-1 regression was a
// 1-wave serial volatile-load tail of ~30us here) ----------------
__global__ __launch_bounds__(256) void merge_kernel(
    const uint2* __restrict__ cand, const float* __restrict__ scores,
    unsigned int* __restrict__ iou_bits, const float* __restrict__ bcePartial,
    float* __restrict__ mergePartial, unsigned int* __restrict__ ctr,
    float* __restrict__ out, int N, int bpb) {
  const int bm = blockIdx.x;
  const int b = bm >> 6;
  const int tid = threadIdx.x;
  const int NC = bpb * KTOP;  // 340 for N=34000

  __shared__ float s_bv[MBUF];
  __shared__ int s_bi[MBUF];
  __shared__ float s_winv[KTOP];
  __shared__ int s_wini[KTOP];
  __shared__ int s_cnt;
  __shared__ float s_d[3];
  __shared__ int s_last;
  __shared__ float s_acc[BQ * 3];  // finalize: {box_sum, npos, bce} per batch
  if (tid == 0) s_cnt = 0;
  if (tid < 3) s_d[tid] = 0.f;
  if (tid < BQ * 3) s_acc[tid] = 0.f;
  __syncthreads();

  const uint2* cbase = cand + (size_t)bm * NC;  // contiguous per (b,m)
  for (int k2 = tid; k2 < NC; k2 += 256) {
    uint2 e = cbase[k2];
    float v = __uint_as_float(e.x);
    if (v > 0.f) {
      int slot = atomicAdd(&s_cnt, 1);  // slot < NC <= MBUF
      s_bv[slot] = v;
      s_bi[slot] = (int)e.y;
    }
  }
  __syncthreads();
  int c = s_cnt;
  __syncthreads();
  if (c > KTOP) {
    select_top10(s_bv, s_bi, s_winv, s_wini, &s_cnt, c, tid);
    __syncthreads();
    c = KTOP;
  }
  if (tid < KTOP && tid < c) {
    float v = s_bv[tid];
    if (v > 0.f) {
      int ix = s_bi[tid];
      unsigned int vb = __float_as_uint(v);
      unsigned int old = atomicMax(&iou_bits[(size_t)b * N + ix], vb);
      if (old < vb) {  // raised this anchor's max: exact delta (telescopes)
        float vold = __uint_as_float(old);  // 0.f when old==0
        bool was = (old != 0u);
        atomicAdd(&s_d[0], was ? (vold - v) : (1.f - v));
        if (!was) atomicAdd(&s_d[1], 1.f);
        atomicAdd(&s_d[2], -scores[(size_t)b * N + ix] * (v - vold));
      }
    }
  }
  __syncthreads();
  if (tid == 0) {
    float4* mp = (float4*)(mergePartial + (size_t)bm * 4);
    *mp = make_float4(s_d[0], s_d[1], s_d[2], 0.f);  // always written
    __threadfence();                                  // release partials
    unsigned int done = atomicAdd(ctr, 1u);           // device-scope RMW
    s_last = (done == (unsigned)(gridDim.x - 1)) ? 1 : 0;
  }
  __syncthreads();
  if (s_last) {
    __threadfence();  // acquire: all other blocks' partials now visible
    // parallel reduction: 256 threads x ~10 loads each (MLP across lanes),
    // accumulate into per-batch LDS cells via LDS float atomics.
    volatile const float* mp = mergePartial;
    for (int i = tid; i < BQ * MQ; i += 256) {
      int bb = i >> 6;
      float a0 = mp[i * 4 + 0];
      float a1 = mp[i * 4 + 1];
      float a2 = mp[i * 4 + 2];
      atomicAdd(&s_acc[bb * 3 + 0], a0);
      atomicAdd(&s_acc[bb * 3 + 1], a1);
      atomicAdd(&s_acc[bb * 3 + 2], a2);
    }
    volatile const float* bp = bcePartial;
    for (int i = tid; i < BQ * bpb; i += 256) {
      int bb = i / bpb;
      atomicAdd(&s_acc[bb * 3 + 2], bp[i]);
    }
    __syncthreads();
    if (tid == 0) {
      float box = 0.f, obj = 0.f;
      for (int bb = 0; bb < BQ; ++bb) {
        float np = s_acc[bb * 3 + 1];
        box += (np > 0.f) ? s_acc[bb * 3 + 0] / fmaxf(np, 1.f) : 0.f;
        obj += s_acc[bb * 3 + 2] / (float)N;
      }
      out[0] = (7.5f * box + obj) / (float)BQ;
      out[1] = box;
      out[2] = obj;
    }
  }
}

extern "C" void kernel_launch(void* const* d_in, const int* in_sizes, int n_in,
                              void* d_out, int out_size, void* d_ws, size_t ws_size,
                              hipStream_t stream) {
  const float* boxes = (const float*)d_in[0];
  const float* scores = (const float*)d_in[1];
  const float* targets = (const float*)d_in[2];
  float* out = (float*)d_out;
  const int N = in_sizes[1] / BQ;  // scores is [B, N]

  const int bpb = (N + APB - 1) / APB;  // 34 for N=34000
  const int nblk = BQ * bpb;            // 272 decode blocks

  char* ws = (char*)d_ws;
  size_t cand_bytes = (size_t)BQ * MQ * bpb * KTOP * sizeof(uint2);
  size_t iou_bytes = (size_t)BQ * N * sizeof(unsigned int);
  size_t bce_bytes = (((size_t)nblk * sizeof(float)) + 255) & ~(size_t)255;
  size_t mp_bytes = (size_t)BQ * MQ * 4 * sizeof(float);

  uint2* cand = (uint2*)ws;                    ws += cand_bytes;
  unsigned int* iou_bits = (unsigned int*)ws;  ws += iou_bytes;
  float* bcePartial = (float*)ws;              ws += bce_bytes;
  float* mergePartial = (float*)ws;            ws += mp_bytes;
  unsigned int* ctr = (unsigned int*)ws;

  // 2 dispatches: no memset (always-written per-block partials; ctr zeroed by
  // decode which fully precedes merge by stream order), no finalize dispatch
  // (folded into merge's last block, now parallel-reduced).
  decode_topk_kernel<<<nblk, 256, 0, stream>>>(boxes, scores, targets,
                                               iou_bits, cand, bcePartial, ctr, N, bpb);
  merge_kernel<<<BQ * MQ, 256, 0, stream>>>(cand, scores, iou_bits, bcePartial,
                                            mergePartial, ctr, out, N, bpb);
}

// Round 3
// 143.823 us; speedup vs baseline: 1.1425x; 1.1074x over previous
//
#include <hip/hip_runtime.h>
#include <math.h>

#define BQ 8
#define MQ 64
#define REGMAX 16
#define KTOP 10
#define EPSQ 1e-7f
#define APB 256   // anchors per decode block (256 threads x 1) -> 1064 blocks = 4.2/CU
#define MBUF 1344 // >= bpb*KTOP = 1330 for N=34000

__device__ __forceinline__ float frcp(float x) { return __builtin_amdgcn_rcpf(x); }

// DFL expected value for one side: 16 named scalar loads (16-deep burst -> MLP).
__device__ __forceinline__ float dfl_side(const float* __restrict__ p, size_t Ns) {
  float x0 = p[0];
  float x1 = p[Ns];
  float x2 = p[2 * Ns];
  float x3 = p[3 * Ns];
  float x4 = p[4 * Ns];
  float x5 = p[5 * Ns];
  float x6 = p[6 * Ns];
  float x7 = p[7 * Ns];
  float x8 = p[8 * Ns];
  float x9 = p[9 * Ns];
  float x10 = p[10 * Ns];
  float x11 = p[11 * Ns];
  float x12 = p[12 * Ns];
  float x13 = p[13 * Ns];
  float x14 = p[14 * Ns];
  float x15 = p[15 * Ns];
  float mx = fmaxf(fmaxf(fmaxf(fmaxf(x0, x1), fmaxf(x2, x3)),
                         fmaxf(fmaxf(x4, x5), fmaxf(x6, x7))),
                   fmaxf(fmaxf(fmaxf(x8, x9), fmaxf(x10, x11)),
                         fmaxf(fmaxf(x12, x13), fmaxf(x14, x15))));
  float s = 0.f, ws = 0.f, e;
  e = __expf(x0 - mx); s += e;
  e = __expf(x1 - mx); s += e; ws += 1.f * e;
  e = __expf(x2 - mx); s += e; ws += 2.f * e;
  e = __expf(x3 - mx); s += e; ws += 3.f * e;
  e = __expf(x4 - mx); s += e; ws += 4.f * e;
  e = __expf(x5 - mx); s += e; ws += 5.f * e;
  e = __expf(x6 - mx); s += e; ws += 6.f * e;
  e = __expf(x7 - mx); s += e; ws += 7.f * e;
  e = __expf(x8 - mx); s += e; ws += 8.f * e;
  e = __expf(x9 - mx); s += e; ws += 9.f * e;
  e = __expf(x10 - mx); s += e; ws += 10.f * e;
  e = __expf(x11 - mx); s += e; ws += 11.f * e;
  e = __expf(x12 - mx); s += e; ws += 12.f * e;
  e = __expf(x13 - mx); s += e; ws += 13.f * e;
  e = __expf(x14 - mx); s += e; ws += 14.f * e;
  e = __expf(x15 - mx); s += e; ws += 15.f * e;
  return ws * frcp(s);
}

// ---------------- kernel 1: decode (1 anchor/thread, 1064 blocks for occupancy)
// + ballot-compacted survivor screen + per-block per-target top-10 ----------------
__global__ __launch_bounds__(256, 4) void decode_topk_kernel(
    const float* __restrict__ boxes, const float* __restrict__ scores,
    const float* __restrict__ targets, unsigned int* __restrict__ iou_bits,
    uint2* __restrict__ cand, float* __restrict__ bcePartial,
    unsigned int* __restrict__ ctr, int N, int bpb) {
  const int tid = threadIdx.x;
  const int b = blockIdx.x / bpb;
  const int blk = blockIdx.x - b * bpb;
  const int a0 = blk * APB;
  const int w = tid >> 6;
  const int l = tid & 63;

  __shared__ float4 s_sv[APB];
  __shared__ float s_at[APB];
  __shared__ int s_ix[APB];
  __shared__ float s_hv[4 * MQ * KTOP];
  __shared__ int s_hi[4 * MQ * KTOP];
  __shared__ uint2 s_mg[MQ * KTOP];
  __shared__ int s_cnt;
  __shared__ float s_bce;
  if (tid == 0) { s_cnt = 0; s_bce = 0.f; }
  // zero the merge-done counter; decode fully precedes merge (stream order).
  if (blockIdx.x == 0 && tid == 0) *ctr = 0u;
  __syncthreads();

  // ---- phase 1: decode 1 anchor/thread, 4 sides of 16-deep load bursts ----
  const int n = a0 + tid;
  float bce0 = 0.f;
  bool pred = false;
  float e0 = 0.f, e1 = 0.f, e2 = 0.f, e3 = 0.f, at = 0.f;
  if (n < N) {
    const size_t i = (size_t)b * N + n;
    iou_bits[i] = 0u;
    float sc = scores[i];
    bce0 = fmaxf(sc, 0.f) + log1pf(__expf(-fabsf(sc)));
    const size_t Ns = (size_t)N;
    const float* base = boxes + (size_t)(b * 64) * Ns + n;
    e0 = dfl_side(base, Ns);
    e1 = dfl_side(base + 16 * Ns, Ns);
    e2 = dfl_side(base + 32 * Ns, Ns);
    e3 = dfl_side(base + 48 * Ns, Ns);
    float w1 = e2 - e0, h1 = e3 - e1;
    if (w1 > 0.f && h1 > 0.f) {  // else ciou<=0 vs every target (ref masks topv>0)
      pred = true;
      at = atanf(w1 * frcp(h1 + EPSQ));
    }
  }
  // ballot compaction: one contended LDS atomic per wave (not per thread)
  {
    unsigned long long mask = __ballot(pred);
    int cnt = __popcll(mask);
    int bslot = 0;
    if (l == 0 && cnt) bslot = atomicAdd(&s_cnt, cnt);
    bslot = __shfl(bslot, 0, 64);
    if (pred) {
      int pos = bslot + __popcll(mask & ((1ull << l) - 1ull));
      s_sv[pos] = make_float4(e0, e1, e2, e3);
      s_at[pos] = at;
      s_ix[pos] = n;
    }
  }
#pragma unroll
  for (int d = 1; d < 64; d <<= 1) bce0 += __shfl_xor(bce0, d, 64);
  if (l == 0) atomicAdd(&s_bce, bce0);
  __syncthreads();
  const int nsurv = s_cnt;
  if (tid == 0) bcePartial[blockIdx.x] = s_bce;  // always written: no memset needed

  // ---- phase 2: lane = target; wave w scans its survivor quarter (LDS broadcast) ----
  const float4 t = ((const float4*)targets)[b * MQ + l];
  const float x21 = t.x, y21 = t.y, x22 = t.z, y22 = t.w;
  const float w2 = x22 - x21, h2 = y22 - y21;
  const float atan_t = atanf(w2 * frcp(h2 + EPSQ));
  const float area2 = w2 * h2, sumx2 = x21 + x22, sumy2 = y21 + y22;
  const float CPI = 4.0f / (float)(M_PI * M_PI);

  float hv0 = 0.f, hv1 = 0.f, hv2 = 0.f, hv3 = 0.f, hv4 = 0.f;
  float hv5 = 0.f, hv6 = 0.f, hv7 = 0.f, hv8 = 0.f, hv9 = 0.f;
  int hi0 = 0, hi1 = 0, hi2 = 0, hi3 = 0, hi4 = 0;
  int hi5 = 0, hi6 = 0, hi7 = 0, hi8 = 0, hi9 = 0;

  const int qlen = (nsurv + 3) >> 2;
  const int j0 = w * qlen;
  const int j1 = min(nsurv, j0 + qlen);
  for (int j = j0; j < j1; ++j) {
    float4 p = s_sv[j];  // same addr across lanes -> LDS broadcast
    float pa = s_at[j];
    int ixj = s_ix[j];
    float x11 = p.x, y11 = p.y, x12 = p.z, y12 = p.w;
    float w1 = x12 - x11, h1 = y12 - y11;
    float iw = fmaxf(fminf(x12, x22) - fmaxf(x11, x21), 0.f);
    float ih = fmaxf(fminf(y12, y22) - fmaxf(y11, y21), 0.f);
    float inter = iw * ih;
    float uni = w1 * h1 + area2 - inter + EPSQ;
    float iou = inter * frcp(uni);
    float cw = fmaxf(x12, x22) - fminf(x11, x21);
    float ch = fmaxf(y12, y22) - fminf(y11, y21);
    float c2 = cw * cw + ch * ch + EPSQ;
    float dx = sumx2 - x11 - x12;
    float dy = sumy2 - y11 - y12;
    float rho2 = (dx * dx + dy * dy) * 0.25f;
    float da = atan_t - pa;
    float v = CPI * da * da;
    float alpha = v * frcp(v - iou + 1.f + EPSQ);
    float ciou = iou - rho2 * frcp(c2) - alpha * v;
    if (ciou > hv9) {
      float cv = ciou;
      int ci = ixj;
#define INS(vk, ik)                         \
  {                                         \
    bool gt = cv > vk;                      \
    float tv_ = vk; int ti_ = ik;           \
    vk = gt ? cv : vk; ik = gt ? ci : ik;   \
    cv = gt ? tv_ : cv; ci = gt ? ti_ : ci; \
  }
      INS(hv0, hi0) INS(hv1, hi1) INS(hv2, hi2) INS(hv3, hi3) INS(hv4, hi4)
      INS(hv5, hi5) INS(hv6, hi6) INS(hv7, hi7) INS(hv8, hi8) INS(hv9, hi9)
#undef INS
    }
  }
  const int hb = (w * MQ + l) * KTOP;
  s_hv[hb + 0] = hv0; s_hi[hb + 0] = hi0;
  s_hv[hb + 1] = hv1; s_hi[hb + 1] = hi1;
  s_hv[hb + 2] = hv2; s_hi[hb + 2] = hi2;
  s_hv[hb + 3] = hv3; s_hi[hb + 3] = hi3;
  s_hv[hb + 4] = hv4; s_hi[hb + 4] = hi4;
  s_hv[hb + 5] = hv5; s_hi[hb + 5] = hi5;
  s_hv[hb + 6] = hv6; s_hi[hb + 6] = hi6;
  s_hv[hb + 7] = hv7; s_hi[hb + 7] = hi7;
  s_hv[hb + 8] = hv8; s_hi[hb + 8] = hi8;
  s_hv[hb + 9] = hv9; s_hi[hb + 9] = hi9;
  __syncthreads();

  // ---- phase 3: wave 0, lane m: 4-way merge -> s_mg ----
  if (w == 0) {
    const int m = l;
    int p0 = 0, p1 = 0, p2 = 0, p3 = 0;
    for (int r = 0; r < KTOP; ++r) {
      float c0 = s_hv[(0 * MQ + m) * KTOP + p0];
      float c1 = s_hv[(1 * MQ + m) * KTOP + p1];
      float c2m = s_hv[(2 * MQ + m) * KTOP + p2];
      float c3 = s_hv[(3 * MQ + m) * KTOP + p3];
      float best = c0; int bw = 0;
      if (c1 > best) { best = c1; bw = 1; }
      if (c2m > best) { best = c2m; bw = 2; }
      if (c3 > best) { best = c3; bw = 3; }
      int psel = (bw == 0) ? p0 : (bw == 1) ? p1 : (bw == 2) ? p2 : p3;
      int bidx = s_hi[(bw * MQ + m) * KTOP + psel];
      s_mg[m * KTOP + r] = make_uint2(__float_as_uint(best), (unsigned)bidx);
      if (bw == 0) p0 = min(p0 + 1, KTOP - 1);
      else if (bw == 1) p1 = min(p1 + 1, KTOP - 1);
      else if (bw == 2) p2 = min(p2 + 1, KTOP - 1);
      else p3 = min(p3 + 1, KTOP - 1);
    }
  }
  __syncthreads();
  // copy-out, TRANSPOSED layout [b][m][blk][r] so merge reads contiguously
  for (int sl = tid; sl < MQ * KTOP; sl += 256) {
    int m = sl / KTOP;
    int r = sl - m * KTOP;
    cand[((size_t)(b * MQ + m) * bpb + blk) * KTOP + r] = s_mg[sl];
  }
}

// ---------------- exact top-10 of LDS buffer (wave 0 only) ----------------
__device__ __forceinline__ void select_top10(
    float* s_bv, int* s_bi, float* s_winv, int* s_wini,
    int* s_cnt, int c, int tid) {
  if (tid < 64) {
    for (int r = 0; r < KTOP; ++r) {
      float bv = 0.f;
      int bs = 0xffff;
      for (int sl = tid; sl < c; sl += 64) {
        float v = s_bv[sl];
        if (v > bv) { bv = v; bs = sl; }
      }
      unsigned long long key =
          ((unsigned long long)__float_as_uint(bv) << 32) | (unsigned int)bs;
#pragma unroll
      for (int d = 1; d < 64; d <<= 1) {
        unsigned long long o = __shfl_xor(key, d, 64);
        if (o > key) key = o;
      }
      if (tid == 0) {
        float wv = __uint_as_float((unsigned int)(key >> 32));
        int ws = (int)(key & 0xffffu);
        s_winv[r] = wv;
        if (wv > 0.f && ws != 0xffff) {
          s_wini[r] = s_bi[ws];
          s_bv[ws] = 0.f;
        } else {
          s_wini[r] = 0;
        }
      }
    }
    if (tid < KTOP) { s_bv[tid] = s_winv[tid]; s_bi[tid] = s_wini[tid]; }
    if (tid == 0) *s_cnt = KTOP;
  }
}

// ---------------- kernel 2: merge 133x10 per (b,m) -> top-10; scatter + exact delta;
// last block finalizes with a parallel reduction ----------------
__global__ __launch_bounds__(256) void merge_kernel(
    const uint2* __restrict__ cand, const float* __restrict__ scores,
    unsigned int* __restrict__ iou_bits, const float* __restrict__ bcePartial,
    float* __restrict__ mergePartial, unsigned int* __restrict__ ctr,
    float* __restrict__ out, int N, int bpb) {
  const int bm = blockIdx.x;
  const int b = bm >> 6;
  const int tid = threadIdx.x;
  const int l = tid & 63;
  const int NC = bpb * KTOP;  // 1330 for N=34000

  __shared__ float s_bv[MBUF];
  __shared__ int s_bi[MBUF];
  __shared__ float s_winv[KTOP];
  __shared__ int s_wini[KTOP];
  __shared__ int s_cnt;
  __shared__ float s_d[3];
  __shared__ int s_last;
  __shared__ float s_acc[BQ * 3];  // finalize: {box_sum, npos, bce} per batch
  if (tid == 0) s_cnt = 0;
  if (tid < 3) s_d[tid] = 0.f;
  if (tid < BQ * 3) s_acc[tid] = 0.f;
  __syncthreads();

  const uint2* cbase = cand + (size_t)bm * NC;  // contiguous per (b,m)
  for (int k2 = tid; k2 < NC; k2 += 256) {
    uint2 e = cbase[k2];
    float v = __uint_as_float(e.x);
    bool p = v > 0.f;
    unsigned long long mask = __ballot(p);  // lane0 active whenever any lane is
    int cnt = __popcll(mask);
    int bslot = 0;
    if (l == 0 && cnt) bslot = atomicAdd(&s_cnt, cnt);
    bslot = __shfl(bslot, 0, 64);
    if (p) {
      int pos = bslot + __popcll(mask & ((1ull << l) - 1ull));
      s_bv[pos] = v;
      s_bi[pos] = (int)e.y;
    }
  }
  __syncthreads();
  int c = s_cnt;
  __syncthreads();
  if (c > KTOP) {
    select_top10(s_bv, s_bi, s_winv, s_wini, &s_cnt, c, tid);
    __syncthreads();
    c = KTOP;
  }
  if (tid < KTOP && tid < c) {
    float v = s_bv[tid];
    if (v > 0.f) {
      int ix = s_bi[tid];
      unsigned int vb = __float_as_uint(v);
      unsigned int old = atomicMax(&iou_bits[(size_t)b * N + ix], vb);
      if (old < vb) {  // raised this anchor's max: exact delta (telescopes)
        float vold = __uint_as_float(old);  // 0.f when old==0
        bool was = (old != 0u);
        atomicAdd(&s_d[0], was ? (vold - v) : (1.f - v));
        if (!was) atomicAdd(&s_d[1], 1.f);
        atomicAdd(&s_d[2], -scores[(size_t)b * N + ix] * (v - vold));
      }
    }
  }
  __syncthreads();
  if (tid == 0) {
    float4* mp = (float4*)(mergePartial + (size_t)bm * 4);
    *mp = make_float4(s_d[0], s_d[1], s_d[2], 0.f);  // always written
    __threadfence();                                  // release partials
    unsigned int done = atomicAdd(ctr, 1u);           // device-scope RMW
    s_last = (done == (unsigned)(gridDim.x - 1)) ? 1 : 0;
  }
  __syncthreads();
  if (s_last) {
    __threadfence();  // acquire: all other blocks' partials now visible
    // parallel reduction: 256 threads, MLP across lanes, LDS float atomics.
    volatile const float* mp = mergePartial;
    for (int i = tid; i < BQ * MQ; i += 256) {
      int bb = i >> 6;
      float a0 = mp[i * 4 + 0];
      float a1 = mp[i * 4 + 1];
      float a2 = mp[i * 4 + 2];
      atomicAdd(&s_acc[bb * 3 + 0], a0);
      atomicAdd(&s_acc[bb * 3 + 1], a1);
      atomicAdd(&s_acc[bb * 3 + 2], a2);
    }
    volatile const float* bp = bcePartial;
    for (int i = tid; i < BQ * bpb; i += 256) {
      int bb = i / bpb;
      atomicAdd(&s_acc[bb * 3 + 2], bp[i]);
    }
    __syncthreads();
    if (tid == 0) {
      float box = 0.f, obj = 0.f;
      for (int bb = 0; bb < BQ; ++bb) {
        float np = s_acc[bb * 3 + 1];
        box += (np > 0.f) ? s_acc[bb * 3 + 0] / fmaxf(np, 1.f) : 0.f;
        obj += s_acc[bb * 3 + 2] / (float)N;
      }
      out[0] = (7.5f * box + obj) / (float)BQ;
      out[1] = box;
      out[2] = obj;
    }
  }
}

extern "C" void kernel_launch(void* const* d_in, const int* in_sizes, int n_in,
                              void* d_out, int out_size, void* d_ws, size_t ws_size,
                              hipStream_t stream) {
  const float* boxes = (const float*)d_in[0];
  const float* scores = (const float*)d_in[1];
  const float* targets = (const float*)d_in[2];
  float* out = (float*)d_out;
  const int N = in_sizes[1] / BQ;  // scores is [B, N]

  const int bpb = (N + APB - 1) / APB;  // 133 for N=34000
  const int nblk = BQ * bpb;            // 1064 decode blocks (~4.2/CU)

  char* ws = (char*)d_ws;
  size_t cand_bytes = (size_t)BQ * MQ * bpb * KTOP * sizeof(uint2);
  size_t iou_bytes = (size_t)BQ * N * sizeof(unsigned int);
  size_t bce_bytes = (((size_t)nblk * sizeof(float)) + 255) & ~(size_t)255;
  size_t mp_bytes = (size_t)BQ * MQ * 4 * sizeof(float);

  uint2* cand = (uint2*)ws;                    ws += cand_bytes;
  unsigned int* iou_bits = (unsigned int*)ws;  ws += iou_bytes;
  float* bcePartial = (float*)ws;              ws += bce_bytes;
  float* mergePartial = (float*)ws;            ws += mp_bytes;
  unsigned int* ctr = (unsigned int*)ws;

  // 2 dispatches: no memset (always-written per-block partials; ctr zeroed by
  // decode which fully precedes merge by stream order), no finalize dispatch
  // (folded into merge's last block, parallel-reduced).
  decode_topk_kernel<<<nblk, 256, 0, stream>>>(boxes, scores, targets,
                                               iou_bits, cand, bcePartial, ctr, N, bpb);
  merge_kernel<<<BQ * MQ, 256, 0, stream>>>(cand, scores, iou_bits, bcePartial,
                                            mergePartial, ctr, out, N, bpb);
}

// Round 4
// 142.545 us; speedup vs baseline: 1.1527x; 1.0090x over previous
//
#include <hip/hip_runtime.h>
#include <math.h>

#define BQ 8
#define MQ 64
#define REGMAX 16
#define KTOP 10
#define EPSQ 1e-7f
#define APB 256   // anchors per decode block (256 threads x 1) -> 1064 blocks
#define MBUF 1344 // >= bpb*KTOP = 1330 for N=34000

__device__ __forceinline__ float frcp(float x) { return __builtin_amdgcn_rcpf(x); }

// 16 named-scalar loads for one DFL side (row-strided; guaranteed register burst)
#define DECL_LOAD16(P, G)                                                      \
  float G##0 = (P)[0], G##1 = (P)[Ns], G##2 = (P)[2 * Ns], G##3 = (P)[3 * Ns], \
        G##4 = (P)[4 * Ns], G##5 = (P)[5 * Ns], G##6 = (P)[6 * Ns],            \
        G##7 = (P)[7 * Ns], G##8 = (P)[8 * Ns], G##9 = (P)[9 * Ns],            \
        G##10 = (P)[10 * Ns], G##11 = (P)[11 * Ns], G##12 = (P)[12 * Ns],      \
        G##13 = (P)[13 * Ns], G##14 = (P)[14 * Ns], G##15 = (P)[15 * Ns];

#define EV16(G, OUT)                                                           \
  {                                                                            \
    float mx = fmaxf(fmaxf(fmaxf(fmaxf(G##0, G##1), fmaxf(G##2, G##3)),        \
                           fmaxf(fmaxf(G##4, G##5), fmaxf(G##6, G##7))),       \
                     fmaxf(fmaxf(fmaxf(G##8, G##9), fmaxf(G##10, G##11)),      \
                           fmaxf(fmaxf(G##12, G##13), fmaxf(G##14, G##15))));  \
    float s = 0.f, ws = 0.f, e;                                                \
    e = __expf(G##0 - mx); s += e;                                             \
    e = __expf(G##1 - mx); s += e; ws += 1.f * e;                              \
    e = __expf(G##2 - mx); s += e; ws += 2.f * e;                              \
    e = __expf(G##3 - mx); s += e; ws += 3.f * e;                              \
    e = __expf(G##4 - mx); s += e; ws += 4.f * e;                              \
    e = __expf(G##5 - mx); s += e; ws += 5.f * e;                              \
    e = __expf(G##6 - mx); s += e; ws += 6.f * e;                              \
    e = __expf(G##7 - mx); s += e; ws += 7.f * e;                              \
    e = __expf(G##8 - mx); s += e; ws += 8.f * e;                              \
    e = __expf(G##9 - mx); s += e; ws += 9.f * e;                              \
    e = __expf(G##10 - mx); s += e; ws += 10.f * e;                            \
    e = __expf(G##11 - mx); s += e; ws += 11.f * e;                            \
    e = __expf(G##12 - mx); s += e; ws += 12.f * e;                            \
    e = __expf(G##13 - mx); s += e; ws += 13.f * e;                            \
    e = __expf(G##14 - mx); s += e; ws += 14.f * e;                            \
    e = __expf(G##15 - mx); s += e; ws += 15.f * e;                            \
    OUT = ws * frcp(s);                                                        \
  }

// ---------------- kernel 1: decode (1 anchor/thread, 64-load burst for max MLP)
// + ballot-compacted survivor screen + per-block per-target top-10 ----------------
__global__ __launch_bounds__(256) void decode_topk_kernel(
    const float* __restrict__ boxes, const float* __restrict__ scores,
    const float* __restrict__ targets, unsigned int* __restrict__ iou_bits,
    uint2* __restrict__ cand, float* __restrict__ bcePartial,
    unsigned int* __restrict__ ctr, int N, int bpb) {
  const int tid = threadIdx.x;
  const int b = blockIdx.x / bpb;
  const int blk = blockIdx.x - b * bpb;
  const int a0 = blk * APB;
  const int w = tid >> 6;
  const int l = tid & 63;

  __shared__ float4 s_sv[APB];
  __shared__ float s_at[APB];
  __shared__ int s_ix[APB];
  __shared__ float s_hv[4 * MQ * KTOP];
  __shared__ int s_hi[4 * MQ * KTOP];
  __shared__ uint2 s_mg[MQ * KTOP];
  __shared__ int s_cnt;
  __shared__ float s_bce;
  if (tid == 0) { s_cnt = 0; s_bce = 0.f; }
  // zero the merge-done counter; decode fully precedes merge (stream order).
  if (blockIdx.x == 0 && tid == 0) *ctr = 0u;
  __syncthreads();

  // ---- phase 1: ALL 64 row-loads issued as one burst (max lines in flight),
  // then 4 softmax EVs computed from registers. No launch_bounds VGPR clamp.
  const int n = a0 + tid;
  float bce0 = 0.f;
  bool pred = false;
  float e0 = 0.f, e1 = 0.f, e2 = 0.f, e3 = 0.f, at = 0.f;
  if (n < N) {
    const size_t i = (size_t)b * N + n;
    iou_bits[i] = 0u;
    const size_t Ns = (size_t)N;
    const float* base = boxes + (size_t)(b * 64) * Ns + n;
    const float* p0 = base;
    const float* p1 = base + 16 * Ns;
    const float* p2 = base + 32 * Ns;
    const float* p3 = base + 48 * Ns;
    DECL_LOAD16(p0, a)
    DECL_LOAD16(p1, bv)
    DECL_LOAD16(p2, c)
    DECL_LOAD16(p3, d)
    float sc = scores[i];
    bce0 = fmaxf(sc, 0.f) + log1pf(__expf(-fabsf(sc)));
    EV16(a, e0)
    EV16(bv, e1)
    EV16(c, e2)
    EV16(d, e3)
    float w1 = e2 - e0, h1 = e3 - e1;
    if (w1 > 0.f && h1 > 0.f) {  // else ciou<=0 vs every target (ref masks topv>0)
      pred = true;
      at = atanf(w1 * frcp(h1 + EPSQ));
    }
  }
  // ballot compaction: one contended LDS atomic per wave (not per thread)
  {
    unsigned long long mask = __ballot(pred);
    int cnt = __popcll(mask);
    int bslot = 0;
    if (l == 0 && cnt) bslot = atomicAdd(&s_cnt, cnt);
    bslot = __shfl(bslot, 0, 64);
    if (pred) {
      int pos = bslot + __popcll(mask & ((1ull << l) - 1ull));
      s_sv[pos] = make_float4(e0, e1, e2, e3);
      s_at[pos] = at;
      s_ix[pos] = n;
    }
  }
#pragma unroll
  for (int d = 1; d < 64; d <<= 1) bce0 += __shfl_xor(bce0, d, 64);
  if (l == 0) atomicAdd(&s_bce, bce0);
  __syncthreads();
  const int nsurv = s_cnt;
  if (tid == 0) bcePartial[blockIdx.x] = s_bce;  // always written: no memset needed

  // ---- phase 2: lane = target; wave w scans its survivor quarter (LDS broadcast) ----
  const float4 t = ((const float4*)targets)[b * MQ + l];
  const float x21 = t.x, y21 = t.y, x22 = t.z, y22 = t.w;
  const float w2 = x22 - x21, h2 = y22 - y21;
  const float atan_t = atanf(w2 * frcp(h2 + EPSQ));
  const float area2 = w2 * h2, sumx2 = x21 + x22, sumy2 = y21 + y22;
  const float CPI = 4.0f / (float)(M_PI * M_PI);

  float hv0 = 0.f, hv1 = 0.f, hv2 = 0.f, hv3 = 0.f, hv4 = 0.f;
  float hv5 = 0.f, hv6 = 0.f, hv7 = 0.f, hv8 = 0.f, hv9 = 0.f;
  int hi0 = 0, hi1 = 0, hi2 = 0, hi3 = 0, hi4 = 0;
  int hi5 = 0, hi6 = 0, hi7 = 0, hi8 = 0, hi9 = 0;

  const int qlen = (nsurv + 3) >> 2;
  const int j0 = w * qlen;
  const int j1 = min(nsurv, j0 + qlen);
  for (int j = j0; j < j1; ++j) {
    float4 p = s_sv[j];  // same addr across lanes -> LDS broadcast
    float pa = s_at[j];
    int ixj = s_ix[j];
    float x11 = p.x, y11 = p.y, x12 = p.z, y12 = p.w;
    float w1 = x12 - x11, h1 = y12 - y11;
    float iw = fmaxf(fminf(x12, x22) - fmaxf(x11, x21), 0.f);
    float ih = fmaxf(fminf(y12, y22) - fmaxf(y11, y21), 0.f);
    float inter = iw * ih;
    float uni = w1 * h1 + area2 - inter + EPSQ;
    float iou = inter * frcp(uni);
    float cw = fmaxf(x12, x22) - fminf(x11, x21);
    float ch = fmaxf(y12, y22) - fminf(y11, y21);
    float c2 = cw * cw + ch * ch + EPSQ;
    float dx = sumx2 - x11 - x12;
    float dy = sumy2 - y11 - y12;
    float rho2 = (dx * dx + dy * dy) * 0.25f;
    float da = atan_t - pa;
    float v = CPI * da * da;
    float alpha = v * frcp(v - iou + 1.f + EPSQ);
    float ciou = iou - rho2 * frcp(c2) - alpha * v;
    if (ciou > hv9) {
      float cv = ciou;
      int ci = ixj;
#define INS(vk, ik)                         \
  {                                         \
    bool gt = cv > vk;                      \
    float tv_ = vk; int ti_ = ik;           \
    vk = gt ? cv : vk; ik = gt ? ci : ik;   \
    cv = gt ? tv_ : cv; ci = gt ? ti_ : ci; \
  }
      INS(hv0, hi0) INS(hv1, hi1) INS(hv2, hi2) INS(hv3, hi3) INS(hv4, hi4)
      INS(hv5, hi5) INS(hv6, hi6) INS(hv7, hi7) INS(hv8, hi8) INS(hv9, hi9)
#undef INS
    }
  }
  const int hb = (w * MQ + l) * KTOP;
  s_hv[hb + 0] = hv0; s_hi[hb + 0] = hi0;
  s_hv[hb + 1] = hv1; s_hi[hb + 1] = hi1;
  s_hv[hb + 2] = hv2; s_hi[hb + 2] = hi2;
  s_hv[hb + 3] = hv3; s_hi[hb + 3] = hi3;
  s_hv[hb + 4] = hv4; s_hi[hb + 4] = hi4;
  s_hv[hb + 5] = hv5; s_hi[hb + 5] = hi5;
  s_hv[hb + 6] = hv6; s_hi[hb + 6] = hi6;
  s_hv[hb + 7] = hv7; s_hi[hb + 7] = hi7;
  s_hv[hb + 8] = hv8; s_hi[hb + 8] = hi8;
  s_hv[hb + 9] = hv9; s_hi[hb + 9] = hi9;
  __syncthreads();

  // ---- phase 3: wave 0, lane m: 4-way merge -> s_mg ----
  if (w == 0) {
    const int m = l;
    int p0 = 0, p1 = 0, p2 = 0, p3 = 0;
    for (int r = 0; r < KTOP; ++r) {
      float c0 = s_hv[(0 * MQ + m) * KTOP + p0];
      float c1 = s_hv[(1 * MQ + m) * KTOP + p1];
      float c2m = s_hv[(2 * MQ + m) * KTOP + p2];
      float c3 = s_hv[(3 * MQ + m) * KTOP + p3];
      float best = c0; int bw = 0;
      if (c1 > best) { best = c1; bw = 1; }
      if (c2m > best) { best = c2m; bw = 2; }
      if (c3 > best) { best = c3; bw = 3; }
      int psel = (bw == 0) ? p0 : (bw == 1) ? p1 : (bw == 2) ? p2 : p3;
      int bidx = s_hi[(bw * MQ + m) * KTOP + psel];
      s_mg[m * KTOP + r] = make_uint2(__float_as_uint(best), (unsigned)bidx);
      if (bw == 0) p0 = min(p0 + 1, KTOP - 1);
      else if (bw == 1) p1 = min(p1 + 1, KTOP - 1);
      else if (bw == 2) p2 = min(p2 + 1, KTOP - 1);
      else p3 = min(p3 + 1, KTOP - 1);
    }
  }
  __syncthreads();
  // copy-out: CONTIGUOUS per-block store (R0 layout; the scattered transposed
  // store across 1064 blocks was costlier than merge's strided read)
  uint2* obase = cand + (size_t)(b * bpb + blk) * (MQ * KTOP);
  for (int sl = tid; sl < MQ * KTOP; sl += 256) obase[sl] = s_mg[sl];
}

// ---------------- exact top-10 of LDS buffer (wave 0 only) ----------------
__device__ __forceinline__ void select_top10(
    float* s_bv, int* s_bi, float* s_winv, int* s_wini,
    int* s_cnt, int c, int tid) {
  if (tid < 64) {
    for (int r = 0; r < KTOP; ++r) {
      float bv = 0.f;
      int bs = 0xffff;
      for (int sl = tid; sl < c; sl += 64) {
        float v = s_bv[sl];
        if (v > bv) { bv = v; bs = sl; }
      }
      unsigned long long key =
          ((unsigned long long)__float_as_uint(bv) << 32) | (unsigned int)bs;
#pragma unroll
      for (int d = 1; d < 64; d <<= 1) {
        unsigned long long o = __shfl_xor(key, d, 64);
        if (o > key) key = o;
      }
      if (tid == 0) {
        float wv = __uint_as_float((unsigned int)(key >> 32));
        int ws = (int)(key & 0xffffu);
        s_winv[r] = wv;
        if (wv > 0.f && ws != 0xffff) {
          s_wini[r] = s_bi[ws];
          s_bv[ws] = 0.f;
        } else {
          s_wini[r] = 0;
        }
      }
    }
    if (tid < KTOP) { s_bv[tid] = s_winv[tid]; s_bi[tid] = s_wini[tid]; }
    if (tid == 0) *s_cnt = KTOP;
  }
}

// ---------------- kernel 2: merge 133x10 per (b,m) -> top-10; scatter + exact delta;
// last block finalizes with a parallel reduction ----------------
__global__ __launch_bounds__(256) void merge_kernel(
    const uint2* __restrict__ cand, const float* __restrict__ scores,
    unsigned int* __restrict__ iou_bits, const float* __restrict__ bcePartial,
    float* __restrict__ mergePartial, unsigned int* __restrict__ ctr,
    float* __restrict__ out, int N, int bpb) {
  const int bm = blockIdx.x;
  const int b = bm >> 6;
  const int m = bm & 63;
  const int tid = threadIdx.x;
  const int l = tid & 63;
  const int NC = bpb * KTOP;  // 1330 for N=34000

  __shared__ float s_bv[MBUF];
  __shared__ int s_bi[MBUF];
  __shared__ float s_winv[KTOP];
  __shared__ int s_wini[KTOP];
  __shared__ int s_cnt;
  __shared__ float s_d[3];
  __shared__ int s_last;
  __shared__ float s_acc[BQ * 3];  // finalize: {box_sum, npos, bce} per batch
  if (tid == 0) s_cnt = 0;
  if (tid < 3) s_d[tid] = 0.f;
  if (tid < BQ * 3) s_acc[tid] = 0.f;
  __syncthreads();

  // strided gather over decode blocks (cand in R0 contiguous-per-block layout)
  for (int k2 = tid; k2 < NC; k2 += 256) {
    int blkk = k2 / KTOP;
    int r = k2 - blkk * KTOP;
    uint2 e = cand[((size_t)(b * bpb + blkk) * MQ + m) * KTOP + r];
    float v = __uint_as_float(e.x);
    bool p = v > 0.f;
    unsigned long long mask = __ballot(p);  // lane0 active whenever any lane is
    int cnt = __popcll(mask);
    int bslot = 0;
    if (l == 0 && cnt) bslot = atomicAdd(&s_cnt, cnt);
    bslot = __shfl(bslot, 0, 64);
    if (p) {
      int pos = bslot + __popcll(mask & ((1ull << l) - 1ull));
      s_bv[pos] = v;
      s_bi[pos] = (int)e.y;
    }
  }
  __syncthreads();
  int c = s_cnt;
  __syncthreads();
  if (c > KTOP) {
    select_top10(s_bv, s_bi, s_winv, s_wini, &s_cnt, c, tid);
    __syncthreads();
    c = KTOP;
  }
  if (tid < KTOP && tid < c) {
    float v = s_bv[tid];
    if (v > 0.f) {
      int ix = s_bi[tid];
      unsigned int vb = __float_as_uint(v);
      unsigned int old = atomicMax(&iou_bits[(size_t)b * N + ix], vb);
      if (old < vb) {  // raised this anchor's max: exact delta (telescopes)
        float vold = __uint_as_float(old);  // 0.f when old==0
        bool was = (old != 0u);
        atomicAdd(&s_d[0], was ? (vold - v) : (1.f - v));
        if (!was) atomicAdd(&s_d[1], 1.f);
        atomicAdd(&s_d[2], -scores[(size_t)b * N + ix] * (v - vold));
      }
    }
  }
  __syncthreads();
  if (tid == 0) {
    float4* mp = (float4*)(mergePartial + (size_t)bm * 4);
    *mp = make_float4(s_d[0], s_d[1], s_d[2], 0.f);  // always written
    __threadfence();                                  // release partials
    unsigned int done = atomicAdd(ctr, 1u);           // device-scope RMW
    s_last = (done == (unsigned)(gridDim.x - 1)) ? 1 : 0;
  }
  __syncthreads();
  if (s_last) {
    __threadfence();  // acquire: all other blocks' partials now visible
    // parallel reduction: 256 threads, MLP across lanes, LDS float atomics.
    volatile const float* mp = mergePartial;
    for (int i = tid; i < BQ * MQ; i += 256) {
      int bb = i >> 6;
      float a0 = mp[i * 4 + 0];
      float a1 = mp[i * 4 + 1];
      float a2 = mp[i * 4 + 2];
      atomicAdd(&s_acc[bb * 3 + 0], a0);
      atomicAdd(&s_acc[bb * 3 + 1], a1);
      atomicAdd(&s_acc[bb * 3 + 2], a2);
    }
    volatile const float* bp = bcePartial;
    for (int i = tid; i < BQ * bpb; i += 256) {
      int bb = i / bpb;
      atomicAdd(&s_acc[bb * 3 + 2], bp[i]);
    }
    __syncthreads();
    if (tid == 0) {
      float box = 0.f, obj = 0.f;
      for (int bb = 0; bb < BQ; ++bb) {
        float np = s_acc[bb * 3 + 1];
        box += (np > 0.f) ? s_acc[bb * 3 + 0] / fmaxf(np, 1.f) : 0.f;
        obj += s_acc[bb * 3 + 2] / (float)N;
      }
      out[0] = (7.5f * box + obj) / (float)BQ;
      out[1] = box;
      out[2] = obj;
    }
  }
}

extern "C" void kernel_launch(void* const* d_in, const int* in_sizes, int n_in,
                              void* d_out, int out_size, void* d_ws, size_t ws_size,
                              hipStream_t stream) {
  const float* boxes = (const float*)d_in[0];
  const float* scores = (const float*)d_in[1];
  const float* targets = (const float*)d_in[2];
  float* out = (float*)d_out;
  const int N = in_sizes[1] / BQ;  // scores is [B, N]

  const int bpb = (N + APB - 1) / APB;  // 133 for N=34000
  const int nblk = BQ * bpb;            // 1064 decode blocks

  char* ws = (char*)d_ws;
  size_t cand_bytes = (size_t)BQ * bpb * MQ * KTOP * sizeof(uint2);
  size_t iou_bytes = (size_t)BQ * N * sizeof(unsigned int);
  size_t bce_bytes = (((size_t)nblk * sizeof(float)) + 255) & ~(size_t)255;
  size_t mp_bytes = (size_t)BQ * MQ * 4 * sizeof(float);

  uint2* cand = (uint2*)ws;                    ws += cand_bytes;
  unsigned int* iou_bits = (unsigned int*)ws;  ws += iou_bytes;
  float* bcePartial = (float*)ws;              ws += bce_bytes;
  float* mergePartial = (float*)ws;            ws += mp_bytes;
  unsigned int* ctr = (unsigned int*)ws;

  // 2 dispatches: no memset (always-written per-block partials; ctr zeroed by
  // decode which fully precedes merge by stream order), no finalize dispatch
  // (folded into merge's last block, parallel-reduced).
  decode_topk_kernel<<<nblk, 256, 0, stream>>>(boxes, scores, targets,
                                               iou_bits, cand, bcePartial, ctr, N, bpb);
  merge_kernel<<<BQ * MQ, 256, 0, stream>>>(cand, scores, iou_bits, bcePartial,
                                            mergePartial, ctr, out, N, bpb);
}